// Round 2
// baseline (149.481 us; speedup 1.0000x reference)
//
#include <hip/hip_runtime.h>
#include <hip/hip_bf16.h>

#define BATCH 4
#define S_LEN 2048
#define D_MOD 256
#define NH 8
#define HDIM 32
#define SCALE_ 0.0625f

typedef short bf16x8 __attribute__((ext_vector_type(8)));
typedef short short4v __attribute__((ext_vector_type(4)));
typedef float f32x4 __attribute__((ext_vector_type(4)));

__device__ __forceinline__ short f2bf(float f) {
    __hip_bfloat16 h = __float2bfloat16(f);
    return *reinterpret_cast<short*>(&h);
}

// ---------------------------------------------------------------------------
// Kernel 1: fused QKV projection.  Block: 256 thr, tile 64 rows x 256 cols
// (loops 4 n-col tiles reusing staged A).  Q,K written row-major bf16;
// V written TRANSPOSED: Vt[((b*8+h)*32+hd)*2048 + s].
// ---------------------------------------------------------------------------
__global__ __launch_bounds__(256) void qkv_proj_kernel(
    const float* __restrict__ q_in, const float* __restrict__ k_in,
    const float* __restrict__ v_in,
    const float* __restrict__ Wq, const float* __restrict__ Wk,
    const float* __restrict__ Wv,
    const float* __restrict__ bq, const float* __restrict__ bk,
    const float* __restrict__ bv,
    short* __restrict__ Qb, short* __restrict__ Kb, short* __restrict__ Vt)
{
    __shared__ short lsA[64][264];   // [row][k], pad +8
    __shared__ short lsW[64][264];   // [n][k]  (W^T)

    const int mt  = blockIdx.x;      // 0..127 (row tile)
    const int seg = blockIdx.y;      // 0=Q 1=K 2=V
    const float* A    = seg == 0 ? q_in : (seg == 1 ? k_in : v_in);
    const float* W    = seg == 0 ? Wq   : (seg == 1 ? Wk   : Wv);
    const float* bias = seg == 0 ? bq   : (seg == 1 ? bk   : bv);
    const int m0 = mt * 64;
    const int tid = threadIdx.x;

    // stage A tile: 64 x 256 fp32 -> bf16 (once)
    {
        const float4* A4 = (const float4*)(A + (size_t)m0 * D_MOD);
        #pragma unroll
        for (int i = 0; i < 16; ++i) {
            int f4  = tid + i * 256;
            int row = f4 >> 6;
            int c4  = f4 & 63;
            float4 v = A4[f4];
            short4v o;
            o.x = f2bf(v.x); o.y = f2bf(v.y); o.z = f2bf(v.z); o.w = f2bf(v.w);
            *(short4v*)&lsA[row][c4 * 4] = o;
        }
    }

    const int w = tid >> 6, l = tid & 63, g = l >> 4, r15 = l & 15;
    const int bidx = m0 >> 11;           // batch of this row tile
    const int s_base = m0 & (S_LEN - 1); // seq offset of this row tile

    for (int nc = 0; nc < 4; ++nc) {
        const int ncol0 = nc * 64;
        __syncthreads();   // prior compute done reading lsW (and lsA visible)
        #pragma unroll
        for (int i = 0; i < 16; ++i) {
            int f4 = tid + i * 256;
            int k  = f4 >> 4;
            int n4 = f4 & 15;
            float4 v = *(const float4*)&W[(size_t)k * D_MOD + ncol0 + n4 * 4];
            lsW[n4 * 4 + 0][k] = f2bf(v.x);
            lsW[n4 * 4 + 1][k] = f2bf(v.y);
            lsW[n4 * 4 + 2][k] = f2bf(v.z);
            lsW[n4 * 4 + 3][k] = f2bf(v.w);
        }
        __syncthreads();

        f32x4 acc[4] = {};
        #pragma unroll
        for (int k0 = 0; k0 < 256; k0 += 32) {
            bf16x8 a = *(const bf16x8*)&lsA[w * 16 + r15][k0 + 8 * g];
            #pragma unroll
            for (int n = 0; n < 4; ++n) {
                bf16x8 b = *(const bf16x8*)&lsW[n * 16 + r15][k0 + 8 * g];
                acc[n] = __builtin_amdgcn_mfma_f32_16x16x32_bf16(a, b, acc[n], 0, 0, 0);
            }
        }

        if (seg < 2) {
            short* Out = seg == 0 ? Qb : Kb;
            #pragma unroll
            for (int n = 0; n < 4; ++n) {
                int col = ncol0 + n * 16 + r15;
                float bval = bias[col];
                #pragma unroll
                for (int r = 0; r < 4; ++r) {
                    int row = m0 + w * 16 + 4 * g + r;
                    Out[(size_t)row * D_MOD + col] = f2bf(acc[n][r] + bval);
                }
            }
        } else {
            // V: transposed store. col -> (h, hd); 4 consecutive s per thread.
            #pragma unroll
            for (int n = 0; n < 4; ++n) {
                int col = ncol0 + n * 16 + r15;
                int h = col >> 5, hd = col & 31;
                float bval = bias[col];
                short4v o;
                #pragma unroll
                for (int r = 0; r < 4; ++r) o[r] = f2bf(acc[n][r] + bval);
                size_t s = s_base + w * 16 + 4 * g;
                *(short4v*)&Vt[((size_t)(bidx * NH + h) * HDIM + hd) * S_LEN + s] = o;
            }
        }
    }
}

// ---------------------------------------------------------------------------
// Kernel 2: causal attention, NO barriers.  Each wave owns 32 q-rows
// (two 16-row fragments) for one (b,h); K and V^T read directly from global;
// P routed through wave-private LDS (row stride 72 shorts = 144 B).
// Block: 4 waves = 4 different (b,h) at the same jq (uniform work).
// ---------------------------------------------------------------------------
__global__ __launch_bounds__(256) void attn_kernel(
    const short* __restrict__ Qb, const short* __restrict__ Kb,
    const short* __restrict__ Vt, short* __restrict__ Ab)
{
    __shared__ short pl[4][32][72];     // per-wave P: [qrow 0..31][key 0..63]

    const int jq = 63 - blockIdx.x;     // descending work for tail balance
    const int tid = threadIdx.x;
    const int w = tid >> 6, l = tid & 63, g = l >> 4, r15 = l & 15;
    const int bh = blockIdx.y * 4 + w;  // 0..31
    const int b = bh >> 3, h = bh & 7;

    const size_t base = (size_t)b * S_LEN * D_MOD + h * HDIM;
    const short* Qp  = Qb + base;
    const short* Kp  = Kb + base;
    const short* Vtp = Vt + (size_t)bh * HDIM * S_LEN;

    const int q0 = jq * 32;
    bf16x8 aq0 = *(const bf16x8*)&Qp[(size_t)(q0 + r15) * D_MOD + 8 * g];
    bf16x8 aq1 = *(const bf16x8*)&Qp[(size_t)(q0 + 16 + r15) * D_MOD + 8 * g];

    f32x4 oacc[2][2] = {};
    float ps0[4] = {}, ps1[4] = {};
    const f32x4 zero = {};
    const int ntiles = (q0 + 32 + 63) >> 6;
    const int qr_base0 = q0 + 4 * g;

    for (int kt = 0; kt < ntiles; ++kt) {
        const int k0 = kt * 64;
        // S = Q K^T ; P = exp(S*scale) masked causal; store P to wave LDS
        #pragma unroll
        for (int n = 0; n < 4; ++n) {
            bf16x8 bk = *(const bf16x8*)&Kp[(size_t)(k0 + n * 16 + r15) * D_MOD + 8 * g];
            f32x4 s0 = __builtin_amdgcn_mfma_f32_16x16x32_bf16(aq0, bk, zero, 0, 0, 0);
            f32x4 s1 = __builtin_amdgcn_mfma_f32_16x16x32_bf16(aq1, bk, zero, 0, 0, 0);
            int key = k0 + n * 16 + r15;
            #pragma unroll
            for (int r = 0; r < 4; ++r) {
                int qr0 = qr_base0 + r;
                float e0 = (key <= qr0)      ? __expf(s0[r] * SCALE_) : 0.0f;
                float e1 = (key <= qr0 + 16) ? __expf(s1[r] * SCALE_) : 0.0f;
                ps0[r] += e0;
                ps1[r] += e1;
                pl[w][4 * g + r][n * 16 + r15]      = f2bf(e0);
                pl[w][16 + 4 * g + r][n * 16 + r15] = f2bf(e1);
            }
        }
        // O += P @ V   (B-fragments straight from transposed Vt in global)
        #pragma unroll
        for (int ks = 0; ks < 2; ++ks) {
            bf16x8 pa0 = *(const bf16x8*)&pl[w][r15][ks * 32 + 8 * g];
            bf16x8 pa1 = *(const bf16x8*)&pl[w][16 + r15][ks * 32 + 8 * g];
            #pragma unroll
            for (int n2 = 0; n2 < 2; ++n2) {
                bf16x8 bv = *(const bf16x8*)&Vtp[(size_t)(n2 * 16 + r15) * S_LEN + k0 + ks * 32 + 8 * g];
                oacc[0][n2] = __builtin_amdgcn_mfma_f32_16x16x32_bf16(pa0, bv, oacc[0][n2], 0, 0, 0);
                oacc[1][n2] = __builtin_amdgcn_mfma_f32_16x16x32_bf16(pa1, bv, oacc[1][n2], 0, 0, 0);
            }
        }
    }

    // row sums across the 16 lanes of each group; normalize; write
    float inv0[4], inv1[4];
    #pragma unroll
    for (int r = 0; r < 4; ++r) {
        float v0 = ps0[r], v1 = ps1[r];
        v0 += __shfl_xor(v0, 1); v1 += __shfl_xor(v1, 1);
        v0 += __shfl_xor(v0, 2); v1 += __shfl_xor(v1, 2);
        v0 += __shfl_xor(v0, 4); v1 += __shfl_xor(v1, 4);
        v0 += __shfl_xor(v0, 8); v1 += __shfl_xor(v1, 8);
        inv0[r] = __fdividef(1.0f, v0);
        inv1[r] = __fdividef(1.0f, v1);
    }
    #pragma unroll
    for (int n2 = 0; n2 < 2; ++n2) {
        int col = h * HDIM + n2 * 16 + r15;
        #pragma unroll
        for (int r = 0; r < 4; ++r) {
            size_t row0 = (size_t)b * S_LEN + q0 + 4 * g + r;
            Ab[row0 * D_MOD + col]              = f2bf(oacc[0][n2][r] * inv0[r]);
            Ab[(row0 + 16) * D_MOD + col]       = f2bf(oacc[1][n2][r] * inv1[r]);
        }
    }
}

// ---------------------------------------------------------------------------
// Kernel 3: output projection.  out = Ab @ Wo + bo, fp32 out.
// Loops 4 n-col tiles reusing staged A.
// ---------------------------------------------------------------------------
__global__ __launch_bounds__(256) void out_proj_kernel(
    const short* __restrict__ Ab, const float* __restrict__ Wo,
    const float* __restrict__ bo, float* __restrict__ out)
{
    __shared__ short lsA[64][264];
    __shared__ short lsW[64][264];

    const int m0 = blockIdx.x * 64;
    const int tid = threadIdx.x;

    {
        const short* Ap = Ab + (size_t)m0 * D_MOD;
        #pragma unroll
        for (int i = 0; i < 8; ++i) {
            int f8  = tid + i * 256;
            int row = f8 >> 5;
            int c8  = f8 & 31;
            *(bf16x8*)&lsA[row][c8 * 8] = *(const bf16x8*)&Ap[f8 * 8];
        }
    }

    const int w = tid >> 6, l = tid & 63, g = l >> 4, r15 = l & 15;

    for (int nc = 0; nc < 4; ++nc) {
        const int ncol0 = nc * 64;
        __syncthreads();
        #pragma unroll
        for (int i = 0; i < 16; ++i) {
            int f4 = tid + i * 256;
            int k  = f4 >> 4;
            int n4 = f4 & 15;
            float4 v = *(const float4*)&Wo[(size_t)k * D_MOD + ncol0 + n4 * 4];
            lsW[n4 * 4 + 0][k] = f2bf(v.x);
            lsW[n4 * 4 + 1][k] = f2bf(v.y);
            lsW[n4 * 4 + 2][k] = f2bf(v.z);
            lsW[n4 * 4 + 3][k] = f2bf(v.w);
        }
        __syncthreads();

        f32x4 acc[4] = {};
        #pragma unroll
        for (int k0 = 0; k0 < 256; k0 += 32) {
            bf16x8 a = *(const bf16x8*)&lsA[w * 16 + r15][k0 + 8 * g];
            #pragma unroll
            for (int n = 0; n < 4; ++n) {
                bf16x8 b = *(const bf16x8*)&lsW[n * 16 + r15][k0 + 8 * g];
                acc[n] = __builtin_amdgcn_mfma_f32_16x16x32_bf16(a, b, acc[n], 0, 0, 0);
            }
        }
        #pragma unroll
        for (int n = 0; n < 4; ++n) {
            int col = ncol0 + n * 16 + r15;
            float bval = bo[col];
            #pragma unroll
            for (int r = 0; r < 4; ++r) {
                int row = m0 + w * 16 + 4 * g + r;
                out[(size_t)row * D_MOD + col] = acc[n][r] + bval;
            }
        }
    }
}

extern "C" void kernel_launch(void* const* d_in, const int* in_sizes, int n_in,
                              void* d_out, int out_size, void* d_ws, size_t ws_size,
                              hipStream_t stream) {
    const float* q_in = (const float*)d_in[0];
    const float* k_in = (const float*)d_in[1];
    const float* v_in = (const float*)d_in[2];
    // d_in[3] = mask: causal tril, applied analytically.
    const float* Wq = (const float*)d_in[4];
    const float* bq = (const float*)d_in[5];
    const float* Wk = (const float*)d_in[6];
    const float* bk = (const float*)d_in[7];
    const float* Wv = (const float*)d_in[8];
    const float* bv = (const float*)d_in[9];
    const float* Wo = (const float*)d_in[10];
    const float* bo = (const float*)d_in[11];
    float* out = (float*)d_out;

    const size_t NTOK = (size_t)BATCH * S_LEN * D_MOD;  // 2M elements
    short* Qb = (short*)d_ws;
    short* Kb = Qb + NTOK;
    short* Vt = Kb + NTOK;   // transposed V: [b*H+h][hd][s]
    short* Ab = Vt + NTOK;

    qkv_proj_kernel<<<dim3(128, 3), 256, 0, stream>>>(
        q_in, k_in, v_in, Wq, Wk, Wv, bq, bk, bv, Qb, Kb, Vt);
    attn_kernel<<<dim3(64, 8), 256, 0, stream>>>(Qb, Kb, Vt, Ab);
    out_proj_kernel<<<128, 256, 0, stream>>>(Ab, Wo, bo, out);
}

// Round 3
// 109.530 us; speedup vs baseline: 1.3648x; 1.3648x over previous
//
#include <hip/hip_runtime.h>
#include <hip/hip_bf16.h>

#define BATCH 4
#define S_LEN 2048
#define D_MOD 256
#define NH 8
#define HDIM 32
#define SCALE_ 0.0625f

typedef short bf16x8 __attribute__((ext_vector_type(8)));
typedef short short4v __attribute__((ext_vector_type(4)));
typedef float f32x4 __attribute__((ext_vector_type(4)));

__device__ __forceinline__ short f2bf(float f) {
    __hip_bfloat16 h = __float2bfloat16(f);
    return *reinterpret_cast<short*>(&h);
}

// ---------------------------------------------------------------------------
// K0: W fp32 [k][n] -> WT bf16 [n][k] for Wq,Wk,Wv,Wo.  grid (4, 32).
// ---------------------------------------------------------------------------
__global__ __launch_bounds__(256) void wtrans_kernel(
    const float* __restrict__ Wq, const float* __restrict__ Wk,
    const float* __restrict__ Wv, const float* __restrict__ Wo,
    short* __restrict__ WT)
{
    const int wsel = blockIdx.x;
    const int k0 = blockIdx.y * 8;
    const float* W = wsel == 0 ? Wq : (wsel == 1 ? Wk : (wsel == 2 ? Wv : Wo));
    short* T = WT + (size_t)wsel * 256 * 256;
    int n = threadIdx.x;
    bf16x8 o;
    #pragma unroll
    for (int kk = 0; kk < 8; ++kk)
        o[kk] = f2bf(W[(size_t)(k0 + kk) * 256 + n]);
    *(bf16x8*)&T[(size_t)n * 256 + k0] = o;
}

// ---------------------------------------------------------------------------
// K1: QKV projection, streaming.  Block 256 thr = 4 waves; block covers 32
// rows; wave = (row-half, col-half) -> 16 rows x 128 cols.  B-fragments
// straight from WT (L2-resident).  Q,K row-major bf16; V transposed
// Vt[((b*8+h)*32+hd)*2048 + s].  grid (256, 3).
// ---------------------------------------------------------------------------
__global__ __launch_bounds__(256) void qkv_proj_kernel(
    const float* __restrict__ q_in, const float* __restrict__ k_in,
    const float* __restrict__ v_in, const short* __restrict__ WT,
    const float* __restrict__ bq, const float* __restrict__ bk,
    const float* __restrict__ bv,
    short* __restrict__ Qb, short* __restrict__ Kb, short* __restrict__ Vt)
{
    __shared__ short lsA[32][264];
    const int mt = blockIdx.x;
    const int seg = blockIdx.y;
    const float* A = seg == 0 ? q_in : (seg == 1 ? k_in : v_in);
    const short* WTs = WT + (size_t)seg * 65536;
    const float* bias = seg == 0 ? bq : (seg == 1 ? bk : bv);
    const int m0 = mt * 32;
    const int tid = threadIdx.x;

    {
        const float4* A4 = (const float4*)(A + (size_t)m0 * D_MOD);
        #pragma unroll
        for (int i = 0; i < 8; ++i) {
            int f4 = tid + i * 256;
            int row = f4 >> 6, c4 = f4 & 63;
            float4 v = A4[f4];
            short4v o;
            o.x = f2bf(v.x); o.y = f2bf(v.y); o.z = f2bf(v.z); o.w = f2bf(v.w);
            *(short4v*)&lsA[row][c4 * 4] = o;
        }
    }
    __syncthreads();

    const int w = tid >> 6, l = tid & 63, g = l >> 4, r15 = l & 15;
    const int rh = w & 1, ch = w >> 1;
    bf16x8 af[8];
    #pragma unroll
    for (int kk = 0; kk < 8; ++kk)
        af[kk] = *(const bf16x8*)&lsA[rh * 16 + r15][kk * 32 + 8 * g];

    const int bidx = m0 >> 11;
    const int s_base = m0 & (S_LEN - 1);

    for (int ntl = 0; ntl < 8; ++ntl) {
        int col = ch * 128 + ntl * 16 + r15;
        f32x4 acc = {};
        #pragma unroll
        for (int kk = 0; kk < 8; ++kk) {
            bf16x8 b = *(const bf16x8*)&WTs[(size_t)col * 256 + kk * 32 + 8 * g];
            acc = __builtin_amdgcn_mfma_f32_16x16x32_bf16(af[kk], b, acc, 0, 0, 0);
        }
        float bval = bias[col];
        if (seg < 2) {
            short* Out = seg == 0 ? Qb : Kb;
            #pragma unroll
            for (int r = 0; r < 4; ++r)
                Out[(size_t)(m0 + rh * 16 + 4 * g + r) * D_MOD + col] = f2bf(acc[r] + bval);
        } else {
            int h = col >> 5, hd = col & 31;
            short4v o;
            #pragma unroll
            for (int r = 0; r < 4; ++r) o[r] = f2bf(acc[r] + bval);
            size_t s = s_base + rh * 16 + 4 * g;
            *(short4v*)&Vt[((size_t)(bidx * NH + h) * HDIM + hd) * S_LEN + s] = o;
        }
    }
}

// ---------------------------------------------------------------------------
// K2: causal attention with block-level key-split.  Block = 4 waves, all on
// the SAME (bh, 32 q-rows); wave w does k-tiles w, w+4, ...  Partial O and
// rowsums combined in LDS (unioned with the P buffer).  grid (64, 32).
// ---------------------------------------------------------------------------
__global__ __launch_bounds__(256) void attn_kernel(
    const short* __restrict__ Qb, const short* __restrict__ Kb,
    const short* __restrict__ Vt, short* __restrict__ Ab)
{
    __shared__ char smem[18432];               // pl (18.4KB) / comb (16.9KB)
    __shared__ float psl[4][2][16];
    short (*pl)[32][72] = (short(*)[32][72])smem;
    float (*comb)[32][33] = (float(*)[32][33])smem;

    const int jq = 63 - blockIdx.x;            // heavy blocks first
    const int bh = blockIdx.y;
    const int b = bh >> 3, h = bh & 7;
    const int tid = threadIdx.x;
    const int w = tid >> 6, l = tid & 63, g = l >> 4, r15 = l & 15;
    const int q0 = jq * 32;

    const size_t base = (size_t)b * S_LEN * D_MOD + h * HDIM;
    const short* Qp = Qb + base;
    const short* Kp = Kb + base;
    const short* Vtp = Vt + (size_t)bh * HDIM * S_LEN;

    bf16x8 aq0 = *(const bf16x8*)&Qp[(size_t)(q0 + r15) * D_MOD + 8 * g];
    bf16x8 aq1 = *(const bf16x8*)&Qp[(size_t)(q0 + 16 + r15) * D_MOD + 8 * g];

    f32x4 oacc[2][2] = {};
    float ps0[4] = {}, ps1[4] = {};
    const f32x4 zero = {};
    const int ntiles = (q0 + 95) >> 6;

    for (int kt = w; kt < ntiles; kt += 4) {
        const int k0 = kt * 64;
        const bool full = (k0 + 63) <= q0;     // wave-uniform
        #pragma unroll
        for (int n = 0; n < 4; ++n) {
            bf16x8 bk = *(const bf16x8*)&Kp[(size_t)(k0 + n * 16 + r15) * D_MOD + 8 * g];
            f32x4 s0 = __builtin_amdgcn_mfma_f32_16x16x32_bf16(aq0, bk, zero, 0, 0, 0);
            f32x4 s1 = __builtin_amdgcn_mfma_f32_16x16x32_bf16(aq1, bk, zero, 0, 0, 0);
            int key = k0 + n * 16 + r15;
            if (full) {
                #pragma unroll
                for (int r = 0; r < 4; ++r) {
                    float e0 = __expf(s0[r] * SCALE_);
                    float e1 = __expf(s1[r] * SCALE_);
                    ps0[r] += e0; ps1[r] += e1;
                    pl[w][4 * g + r][n * 16 + r15]      = f2bf(e0);
                    pl[w][16 + 4 * g + r][n * 16 + r15] = f2bf(e1);
                }
            } else {
                #pragma unroll
                for (int r = 0; r < 4; ++r) {
                    int qr = q0 + 4 * g + r;
                    float e0 = (key <= qr)      ? __expf(s0[r] * SCALE_) : 0.0f;
                    float e1 = (key <= qr + 16) ? __expf(s1[r] * SCALE_) : 0.0f;
                    ps0[r] += e0; ps1[r] += e1;
                    pl[w][4 * g + r][n * 16 + r15]      = f2bf(e0);
                    pl[w][16 + 4 * g + r][n * 16 + r15] = f2bf(e1);
                }
            }
        }
        #pragma unroll
        for (int ks = 0; ks < 2; ++ks) {
            bf16x8 pa0 = *(const bf16x8*)&pl[w][r15][ks * 32 + 8 * g];
            bf16x8 pa1 = *(const bf16x8*)&pl[w][16 + r15][ks * 32 + 8 * g];
            #pragma unroll
            for (int n2 = 0; n2 < 2; ++n2) {
                bf16x8 bv = *(const bf16x8*)&Vtp[(size_t)(n2 * 16 + r15) * S_LEN + k0 + ks * 32 + 8 * g];
                oacc[0][n2] = __builtin_amdgcn_mfma_f32_16x16x32_bf16(pa0, bv, oacc[0][n2], 0, 0, 0);
                oacc[1][n2] = __builtin_amdgcn_mfma_f32_16x16x32_bf16(pa1, bv, oacc[1][n2], 0, 0, 0);
            }
        }
    }

    // per-wave rowsum reduce across the 16 key-lanes
    #pragma unroll
    for (int r = 0; r < 4; ++r) {
        float v0 = ps0[r], v1 = ps1[r];
        v0 += __shfl_xor(v0, 1); v1 += __shfl_xor(v1, 1);
        v0 += __shfl_xor(v0, 2); v1 += __shfl_xor(v1, 2);
        v0 += __shfl_xor(v0, 4); v1 += __shfl_xor(v1, 4);
        v0 += __shfl_xor(v0, 8); v1 += __shfl_xor(v1, 8);
        ps0[r] = v0; ps1[r] = v1;
    }

    __syncthreads();   // all waves done with pl -> reuse as comb
    #pragma unroll
    for (int n2 = 0; n2 < 2; ++n2) {
        #pragma unroll
        for (int r = 0; r < 4; ++r) {
            comb[w][4 * g + r][n2 * 16 + r15]      = oacc[0][n2][r];
            comb[w][16 + 4 * g + r][n2 * 16 + r15] = oacc[1][n2][r];
        }
    }
    if (r15 == 0) {
        #pragma unroll
        for (int r = 0; r < 4; ++r) {
            psl[w][0][4 * g + r] = ps0[r];
            psl[w][1][4 * g + r] = ps1[r];
        }
    }
    __syncthreads();

    // epilogue: 256 threads cover 32 q x 32 hd
    {
        int q = tid >> 3, hd0 = (tid & 7) * 4;
        int qf = q >> 4, q15 = q & 15;
        float ps = psl[0][qf][q15] + psl[1][qf][q15] + psl[2][qf][q15] + psl[3][qf][q15];
        float inv = __fdividef(1.0f, ps);
        short4v o;
        #pragma unroll
        for (int j = 0; j < 4; ++j) {
            float v = comb[0][q][hd0 + j] + comb[1][q][hd0 + j]
                    + comb[2][q][hd0 + j] + comb[3][q][hd0 + j];
            o[j] = f2bf(v * inv);
        }
        *(short4v*)&Ab[((size_t)b * S_LEN + q0 + q) * D_MOD + h * HDIM + hd0] = o;
    }
}

// ---------------------------------------------------------------------------
// K3: output projection, streaming (no LDS).  Block 256 = 4 waves; block =
// 32 rows; wave = (row-half, col-half).  grid 256.
// ---------------------------------------------------------------------------
__global__ __launch_bounds__(256) void out_proj_kernel(
    const short* __restrict__ Ab, const short* __restrict__ WTo,
    const float* __restrict__ bo, float* __restrict__ out)
{
    const int m0 = blockIdx.x * 32;
    const int tid = threadIdx.x;
    const int w = tid >> 6, l = tid & 63, g = l >> 4, r15 = l & 15;
    const int rh = w & 1, ch = w >> 1;

    bf16x8 af[8];
    #pragma unroll
    for (int kk = 0; kk < 8; ++kk)
        af[kk] = *(const bf16x8*)&Ab[(size_t)(m0 + rh * 16 + r15) * D_MOD + kk * 32 + 8 * g];

    for (int ntl = 0; ntl < 8; ++ntl) {
        int col = ch * 128 + ntl * 16 + r15;
        f32x4 acc = {};
        #pragma unroll
        for (int kk = 0; kk < 8; ++kk) {
            bf16x8 bfr = *(const bf16x8*)&WTo[(size_t)col * 256 + kk * 32 + 8 * g];
            acc = __builtin_amdgcn_mfma_f32_16x16x32_bf16(af[kk], bfr, acc, 0, 0, 0);
        }
        float bval = bo[col];
        #pragma unroll
        for (int r = 0; r < 4; ++r)
            out[(size_t)(m0 + rh * 16 + 4 * g + r) * D_MOD + col] = acc[r] + bval;
    }
}

extern "C" void kernel_launch(void* const* d_in, const int* in_sizes, int n_in,
                              void* d_out, int out_size, void* d_ws, size_t ws_size,
                              hipStream_t stream) {
    const float* q_in = (const float*)d_in[0];
    const float* k_in = (const float*)d_in[1];
    const float* v_in = (const float*)d_in[2];
    // d_in[3] = mask: causal tril, applied analytically.
    const float* Wq = (const float*)d_in[4];
    const float* bq = (const float*)d_in[5];
    const float* Wk = (const float*)d_in[6];
    const float* bk = (const float*)d_in[7];
    const float* Wv = (const float*)d_in[8];
    const float* bv = (const float*)d_in[9];
    const float* Wo = (const float*)d_in[10];
    const float* bo = (const float*)d_in[11];
    float* out = (float*)d_out;

    const size_t NTOK = (size_t)BATCH * S_LEN * D_MOD;  // 2M elements
    short* WT = (short*)d_ws;           // 4 x 256 x 256 bf16 = 512 KB
    short* Qb = WT + 4 * 65536;
    short* Kb = Qb + NTOK;
    short* Vt = Kb + NTOK;              // transposed V: [b*H+h][hd][s]
    short* Ab = Vt + NTOK;

    wtrans_kernel<<<dim3(4, 32), 256, 0, stream>>>(Wq, Wk, Wv, Wo, WT);
    qkv_proj_kernel<<<dim3(256, 3), 256, 0, stream>>>(
        q_in, k_in, v_in, WT, bq, bk, bv, Qb, Kb, Vt);
    attn_kernel<<<dim3(64, 32), 256, 0, stream>>>(Qb, Kb, Vt, Ab);
    out_proj_kernel<<<256, 256, 0, stream>>>(Ab, WT + 3 * 65536, bo, out);
}

// Round 4
// 74.647 us; speedup vs baseline: 2.0025x; 1.4673x over previous
//
#include <hip/hip_runtime.h>
#include <hip/hip_bf16.h>

#define BATCH 4
#define S_LEN 2048
#define D_MOD 256
#define NH 8
#define HDIM 32
#define SCALE_ 0.0625f

typedef short bf16x8 __attribute__((ext_vector_type(8)));
typedef short short4v __attribute__((ext_vector_type(4)));
typedef float f32x4 __attribute__((ext_vector_type(4)));

__device__ __forceinline__ short f2bf(float f) {
    __hip_bfloat16 h = __float2bfloat16(f);
    return *reinterpret_cast<short*>(&h);
}

// ---------------------------------------------------------------------------
// K0: W fp32 [k][n] -> WT bf16 [n][k] for Wq,Wk,Wv,Wo.  grid (4, 32).
// ---------------------------------------------------------------------------
__global__ __launch_bounds__(256) void wtrans_kernel(
    const float* __restrict__ Wq, const float* __restrict__ Wk,
    const float* __restrict__ Wv, const float* __restrict__ Wo,
    short* __restrict__ WT)
{
    const int wsel = blockIdx.x;
    const int k0 = blockIdx.y * 8;
    const float* W = wsel == 0 ? Wq : (wsel == 1 ? Wk : (wsel == 2 ? Wv : Wo));
    short* T = WT + (size_t)wsel * 256 * 256;
    int n = threadIdx.x;
    bf16x8 o;
    #pragma unroll
    for (int kk = 0; kk < 8; ++kk)
        o[kk] = f2bf(W[(size_t)(k0 + kk) * 256 + n]);
    *(bf16x8*)&T[(size_t)n * 256 + k0] = o;
}

// ---------------------------------------------------------------------------
// K1: QKV projection, streaming.  Block 256 thr = 4 waves over 32 rows;
// wave w = col-quarter [64w,64w+64), BOTH 16-row fragments (2 acc chains).
// Q,K stored PACKED per head: [bh][s][32].  V transposed: [bh][hd][s].
// grid (256, 3).
// ---------------------------------------------------------------------------
__global__ __launch_bounds__(256) void qkv_proj_kernel(
    const float* __restrict__ q_in, const float* __restrict__ k_in,
    const float* __restrict__ v_in, const short* __restrict__ WT,
    const float* __restrict__ bq, const float* __restrict__ bk,
    const float* __restrict__ bv,
    short* __restrict__ Qp, short* __restrict__ Kp, short* __restrict__ Vt)
{
    __shared__ short lsA[32][264];
    const int mt = blockIdx.x;
    const int seg = blockIdx.y;
    const float* A = seg == 0 ? q_in : (seg == 1 ? k_in : v_in);
    const short* WTs = WT + (size_t)seg * 65536;
    const float* bias = seg == 0 ? bq : (seg == 1 ? bk : bv);
    const int m0 = mt * 32;
    const int tid = threadIdx.x;

    {
        const float4* A4 = (const float4*)(A + (size_t)m0 * D_MOD);
        #pragma unroll
        for (int i = 0; i < 8; ++i) {
            int f4 = tid + i * 256;
            int row = f4 >> 6, c4 = f4 & 63;
            float4 v = A4[f4];
            short4v o;
            o.x = f2bf(v.x); o.y = f2bf(v.y); o.z = f2bf(v.z); o.w = f2bf(v.w);
            *(short4v*)&lsA[row][c4 * 4] = o;
        }
    }
    __syncthreads();

    const int w = tid >> 6, l = tid & 63, g = l >> 4, r15 = l & 15;
    bf16x8 af[2][8];
    #pragma unroll
    for (int f = 0; f < 2; ++f)
        #pragma unroll
        for (int kk = 0; kk < 8; ++kk)
            af[f][kk] = *(const bf16x8*)&lsA[f * 16 + r15][kk * 32 + 8 * g];

    const int bidx = m0 >> 11;
    const int s_base = m0 & (S_LEN - 1);

    #pragma unroll
    for (int ntl = 0; ntl < 4; ++ntl) {
        int col = w * 64 + ntl * 16 + r15;
        f32x4 acc0 = {}, acc1 = {};
        #pragma unroll
        for (int kk = 0; kk < 8; ++kk) {
            bf16x8 b = *(const bf16x8*)&WTs[(size_t)col * 256 + kk * 32 + 8 * g];
            acc0 = __builtin_amdgcn_mfma_f32_16x16x32_bf16(af[0][kk], b, acc0, 0, 0, 0);
            acc1 = __builtin_amdgcn_mfma_f32_16x16x32_bf16(af[1][kk], b, acc1, 0, 0, 0);
        }
        float bval = bias[col];
        int h = col >> 5, hd = col & 31;
        if (seg < 2) {
            short* Out = seg == 0 ? Qp : Kp;
            short* Outh = Out + ((size_t)(bidx * NH + h) * S_LEN) * HDIM;
            #pragma unroll
            for (int r = 0; r < 4; ++r) {
                int s0 = s_base + 4 * g + r;
                Outh[(size_t)s0 * HDIM + hd]        = f2bf(acc0[r] + bval);
                Outh[(size_t)(s0 + 16) * HDIM + hd] = f2bf(acc1[r] + bval);
            }
        } else {
            short* Vh = Vt + ((size_t)(bidx * NH + h) * HDIM + hd) * S_LEN;
            short4v o0, o1;
            #pragma unroll
            for (int r = 0; r < 4; ++r) { o0[r] = f2bf(acc0[r] + bval); o1[r] = f2bf(acc1[r] + bval); }
            size_t s = s_base + 4 * g;
            *(short4v*)&Vh[s]      = o0;
            *(short4v*)&Vh[s + 16] = o1;
        }
    }
}

// ---------------------------------------------------------------------------
// K2: causal attention, block-level key-split, XCD-locality swizzle.
// Block = 4 waves on SAME (bh, 32 q-rows); wave w does k-tiles w, w+4, ...
// XCD x (= idx%8) owns bh in {4x..4x+3} -> per-XCD K/Q/V ~1.5MB, L2-resident.
// K,Q packed [bh][s][32]; V^T [bh][hd][s].  grid 2048.
// ---------------------------------------------------------------------------
__global__ __launch_bounds__(256) void attn_kernel(
    const short* __restrict__ Qp, const short* __restrict__ Kp,
    const short* __restrict__ Vt, short* __restrict__ Ab)
{
    __shared__ char smem[18432];               // pl / comb union
    __shared__ float psl[4][2][16];
    short (*pl)[32][72] = (short(*)[32][72])smem;
    float (*comb)[32][33] = (float(*)[32][33])smem;

    const int idx = blockIdx.x;
    const int bh = 4 * (idx & 7) + ((idx >> 3) & 3);
    const int jq = idx >> 5;
    const int b = bh >> 3, h = bh & 7;
    const int tid = threadIdx.x;
    const int w = tid >> 6, l = tid & 63, g = l >> 4, r15 = l & 15;
    const int q0 = jq * 32;

    const short* Qph = Qp + (size_t)bh * S_LEN * HDIM;
    const short* Kph = Kp + (size_t)bh * S_LEN * HDIM;
    const short* Vtp = Vt + (size_t)bh * HDIM * S_LEN;

    bf16x8 aq0 = *(const bf16x8*)&Qph[(size_t)(q0 + r15) * HDIM + 8 * g];
    bf16x8 aq1 = *(const bf16x8*)&Qph[(size_t)(q0 + 16 + r15) * HDIM + 8 * g];

    f32x4 oacc[2][2] = {};
    float ps0[4] = {}, ps1[4] = {};
    const f32x4 zero = {};
    const int ntiles = (q0 + 95) >> 6;

    for (int kt = w; kt < ntiles; kt += 4) {
        const int k0 = kt * 64;
        const bool full = (k0 + 63) <= q0;     // wave-uniform
        #pragma unroll
        for (int n = 0; n < 4; ++n) {
            bf16x8 bk = *(const bf16x8*)&Kph[(size_t)(k0 + n * 16 + r15) * HDIM + 8 * g];
            f32x4 s0 = __builtin_amdgcn_mfma_f32_16x16x32_bf16(aq0, bk, zero, 0, 0, 0);
            f32x4 s1 = __builtin_amdgcn_mfma_f32_16x16x32_bf16(aq1, bk, zero, 0, 0, 0);
            int key = k0 + n * 16 + r15;
            if (full) {
                #pragma unroll
                for (int r = 0; r < 4; ++r) {
                    float e0 = __expf(s0[r] * SCALE_);
                    float e1 = __expf(s1[r] * SCALE_);
                    ps0[r] += e0; ps1[r] += e1;
                    pl[w][4 * g + r][n * 16 + r15]      = f2bf(e0);
                    pl[w][16 + 4 * g + r][n * 16 + r15] = f2bf(e1);
                }
            } else {
                #pragma unroll
                for (int r = 0; r < 4; ++r) {
                    int qr = q0 + 4 * g + r;
                    float e0 = (key <= qr)      ? __expf(s0[r] * SCALE_) : 0.0f;
                    float e1 = (key <= qr + 16) ? __expf(s1[r] * SCALE_) : 0.0f;
                    ps0[r] += e0; ps1[r] += e1;
                    pl[w][4 * g + r][n * 16 + r15]      = f2bf(e0);
                    pl[w][16 + 4 * g + r][n * 16 + r15] = f2bf(e1);
                }
            }
        }
        #pragma unroll
        for (int ks = 0; ks < 2; ++ks) {
            bf16x8 pa0 = *(const bf16x8*)&pl[w][r15][ks * 32 + 8 * g];
            bf16x8 pa1 = *(const bf16x8*)&pl[w][16 + r15][ks * 32 + 8 * g];
            #pragma unroll
            for (int n2 = 0; n2 < 2; ++n2) {
                bf16x8 bv = *(const bf16x8*)&Vtp[(size_t)(n2 * 16 + r15) * S_LEN + k0 + ks * 32 + 8 * g];
                oacc[0][n2] = __builtin_amdgcn_mfma_f32_16x16x32_bf16(pa0, bv, oacc[0][n2], 0, 0, 0);
                oacc[1][n2] = __builtin_amdgcn_mfma_f32_16x16x32_bf16(pa1, bv, oacc[1][n2], 0, 0, 0);
            }
        }
    }

    #pragma unroll
    for (int r = 0; r < 4; ++r) {
        float v0 = ps0[r], v1 = ps1[r];
        v0 += __shfl_xor(v0, 1); v1 += __shfl_xor(v1, 1);
        v0 += __shfl_xor(v0, 2); v1 += __shfl_xor(v1, 2);
        v0 += __shfl_xor(v0, 4); v1 += __shfl_xor(v1, 4);
        v0 += __shfl_xor(v0, 8); v1 += __shfl_xor(v1, 8);
        ps0[r] = v0; ps1[r] = v1;
    }

    __syncthreads();   // all waves done with pl -> reuse as comb
    #pragma unroll
    for (int n2 = 0; n2 < 2; ++n2) {
        #pragma unroll
        for (int r = 0; r < 4; ++r) {
            comb[w][4 * g + r][n2 * 16 + r15]      = oacc[0][n2][r];
            comb[w][16 + 4 * g + r][n2 * 16 + r15] = oacc[1][n2][r];
        }
    }
    if (r15 == 0) {
        #pragma unroll
        for (int r = 0; r < 4; ++r) {
            psl[w][0][4 * g + r] = ps0[r];
            psl[w][1][4 * g + r] = ps1[r];
        }
    }
    __syncthreads();

    {
        int q = tid >> 3, hd0 = (tid & 7) * 4;
        int qf = q >> 4, q15 = q & 15;
        float ps = psl[0][qf][q15] + psl[1][qf][q15] + psl[2][qf][q15] + psl[3][qf][q15];
        float inv = __fdividef(1.0f, ps);
        short4v o;
        #pragma unroll
        for (int j = 0; j < 4; ++j) {
            float v = comb[0][q][hd0 + j] + comb[1][q][hd0 + j]
                    + comb[2][q][hd0 + j] + comb[3][q][hd0 + j];
            o[j] = f2bf(v * inv);
        }
        *(short4v*)&Ab[((size_t)b * S_LEN + q0 + q) * D_MOD + h * HDIM + hd0] = o;
    }
}

// ---------------------------------------------------------------------------
// K3: output projection, streaming (no LDS).  Block = 4 waves over 32 rows;
// wave w = col-quarter, both row fragments.  grid 256.
// ---------------------------------------------------------------------------
__global__ __launch_bounds__(256) void out_proj_kernel(
    const short* __restrict__ Ab, const short* __restrict__ WTo,
    const float* __restrict__ bo, float* __restrict__ out)
{
    const int m0 = blockIdx.x * 32;
    const int tid = threadIdx.x;
    const int w = tid >> 6, l = tid & 63, g = l >> 4, r15 = l & 15;

    bf16x8 af[2][8];
    #pragma unroll
    for (int f = 0; f < 2; ++f)
        #pragma unroll
        for (int kk = 0; kk < 8; ++kk)
            af[f][kk] = *(const bf16x8*)&Ab[(size_t)(m0 + f * 16 + r15) * D_MOD + kk * 32 + 8 * g];

    #pragma unroll
    for (int ntl = 0; ntl < 4; ++ntl) {
        int col = w * 64 + ntl * 16 + r15;
        f32x4 acc0 = {}, acc1 = {};
        #pragma unroll
        for (int kk = 0; kk < 8; ++kk) {
            bf16x8 bfr = *(const bf16x8*)&WTo[(size_t)col * 256 + kk * 32 + 8 * g];
            acc0 = __builtin_amdgcn_mfma_f32_16x16x32_bf16(af[0][kk], bfr, acc0, 0, 0, 0);
            acc1 = __builtin_amdgcn_mfma_f32_16x16x32_bf16(af[1][kk], bfr, acc1, 0, 0, 0);
        }
        float bval = bo[col];
        #pragma unroll
        for (int r = 0; r < 4; ++r) {
            out[(size_t)(m0 + 4 * g + r) * D_MOD + col]      = acc0[r] + bval;
            out[(size_t)(m0 + 16 + 4 * g + r) * D_MOD + col] = acc1[r] + bval;
        }
    }
}

extern "C" void kernel_launch(void* const* d_in, const int* in_sizes, int n_in,
                              void* d_out, int out_size, void* d_ws, size_t ws_size,
                              hipStream_t stream) {
    const float* q_in = (const float*)d_in[0];
    const float* k_in = (const float*)d_in[1];
    const float* v_in = (const float*)d_in[2];
    // d_in[3] = mask: causal tril, applied analytically.
    const float* Wq = (const float*)d_in[4];
    const float* bq = (const float*)d_in[5];
    const float* Wk = (const float*)d_in[6];
    const float* bk = (const float*)d_in[7];
    const float* Wv = (const float*)d_in[8];
    const float* bv = (const float*)d_in[9];
    const float* Wo = (const float*)d_in[10];
    const float* bo = (const float*)d_in[11];
    float* out = (float*)d_out;

    const size_t NTOK = (size_t)BATCH * S_LEN * D_MOD;  // 2M elements
    short* WT = (short*)d_ws;           // 4 x 256 x 256 bf16 = 512 KB
    short* Qp = WT + 4 * 65536;         // packed [bh][s][32]
    short* Kp = Qp + NTOK;              // packed [bh][s][32]
    short* Vt = Kp + NTOK;              // transposed [bh][hd][s]
    short* Ab = Vt + NTOK;              // [b][s][256]

    wtrans_kernel<<<dim3(4, 32), 256, 0, stream>>>(Wq, Wk, Wv, Wo, WT);
    qkv_proj_kernel<<<dim3(256, 3), 256, 0, stream>>>(
        q_in, k_in, v_in, WT, bq, bk, bv, Qp, Kp, Vt);
    attn_kernel<<<2048, 256, 0, stream>>>(Qp, Kp, Vt, Ab);
    out_proj_kernel<<<256, 256, 0, stream>>>(Ab, WT + 3 * 65536, bo, out);
}

// Round 5
// 71.613 us; speedup vs baseline: 2.0873x; 1.0424x over previous
//
#include <hip/hip_runtime.h>
#include <hip/hip_bf16.h>

#define BATCH 4
#define S_LEN 2048
#define D_MOD 256
#define NH 8
#define HDIM 32
#define SCALE_ 0.0625f

typedef short bf16x8 __attribute__((ext_vector_type(8)));
typedef short short4v __attribute__((ext_vector_type(4)));
typedef float f32x4 __attribute__((ext_vector_type(4)));

__device__ __forceinline__ short f2bf(float f) {
    __hip_bfloat16 h = __float2bfloat16(f);
    return *reinterpret_cast<short*>(&h);
}

// ---------------------------------------------------------------------------
// K0: W fp32 [k][n] -> WT bf16 [n][k] for Wq,Wk,Wv,Wo.  grid (4, 32).
// ---------------------------------------------------------------------------
__global__ __launch_bounds__(256) void wtrans_kernel(
    const float* __restrict__ Wq, const float* __restrict__ Wk,
    const float* __restrict__ Wv, const float* __restrict__ Wo,
    short* __restrict__ WT)
{
    const int wsel = blockIdx.x;
    const int k0 = blockIdx.y * 8;
    const float* W = wsel == 0 ? Wq : (wsel == 1 ? Wk : (wsel == 2 ? Wv : Wo));
    short* T = WT + (size_t)wsel * 256 * 256;
    int n = threadIdx.x;
    bf16x8 o;
    #pragma unroll
    for (int kk = 0; kk < 8; ++kk)
        o[kk] = f2bf(W[(size_t)(k0 + kk) * 256 + n]);
    *(bf16x8*)&T[(size_t)n * 256 + k0] = o;
}

// ---------------------------------------------------------------------------
// K1: QKV projection, streaming.  Block 256 thr = 4 waves over 32 rows;
// wave w = col-quarter [64w,64w+64), BOTH 16-row fragments (2 acc chains).
// Q,K stored PACKED per head: [bh][s][32].  V transposed: [bh][hd][s].
// grid (256, 3).
// ---------------------------------------------------------------------------
__global__ __launch_bounds__(256) void qkv_proj_kernel(
    const float* __restrict__ q_in, const float* __restrict__ k_in,
    const float* __restrict__ v_in, const short* __restrict__ WT,
    const float* __restrict__ bq, const float* __restrict__ bk,
    const float* __restrict__ bv,
    short* __restrict__ Qp, short* __restrict__ Kp, short* __restrict__ Vt)
{
    __shared__ short lsA[32][264];
    const int mt = blockIdx.x;
    const int seg = blockIdx.y;
    const float* A = seg == 0 ? q_in : (seg == 1 ? k_in : v_in);
    const short* WTs = WT + (size_t)seg * 65536;
    const float* bias = seg == 0 ? bq : (seg == 1 ? bk : bv);
    const int m0 = mt * 32;
    const int tid = threadIdx.x;

    {
        const float4* A4 = (const float4*)(A + (size_t)m0 * D_MOD);
        #pragma unroll
        for (int i = 0; i < 8; ++i) {
            int f4 = tid + i * 256;
            int row = f4 >> 6, c4 = f4 & 63;
            float4 v = A4[f4];
            short4v o;
            o.x = f2bf(v.x); o.y = f2bf(v.y); o.z = f2bf(v.z); o.w = f2bf(v.w);
            *(short4v*)&lsA[row][c4 * 4] = o;
        }
    }
    __syncthreads();

    const int w = tid >> 6, l = tid & 63, g = l >> 4, r15 = l & 15;
    bf16x8 af[2][8];
    #pragma unroll
    for (int f = 0; f < 2; ++f)
        #pragma unroll
        for (int kk = 0; kk < 8; ++kk)
            af[f][kk] = *(const bf16x8*)&lsA[f * 16 + r15][kk * 32 + 8 * g];

    const int bidx = m0 >> 11;
    const int s_base = m0 & (S_LEN - 1);

    #pragma unroll
    for (int ntl = 0; ntl < 4; ++ntl) {
        int col = w * 64 + ntl * 16 + r15;
        f32x4 acc0 = {}, acc1 = {};
        #pragma unroll
        for (int kk = 0; kk < 8; ++kk) {
            bf16x8 b = *(const bf16x8*)&WTs[(size_t)col * 256 + kk * 32 + 8 * g];
            acc0 = __builtin_amdgcn_mfma_f32_16x16x32_bf16(af[0][kk], b, acc0, 0, 0, 0);
            acc1 = __builtin_amdgcn_mfma_f32_16x16x32_bf16(af[1][kk], b, acc1, 0, 0, 0);
        }
        float bval = bias[col];
        int h = col >> 5, hd = col & 31;
        if (seg < 2) {
            short* Out = seg == 0 ? Qp : Kp;
            short* Outh = Out + ((size_t)(bidx * NH + h) * S_LEN) * HDIM;
            #pragma unroll
            for (int r = 0; r < 4; ++r) {
                int s0 = s_base + 4 * g + r;
                Outh[(size_t)s0 * HDIM + hd]        = f2bf(acc0[r] + bval);
                Outh[(size_t)(s0 + 16) * HDIM + hd] = f2bf(acc1[r] + bval);
            }
        } else {
            short* Vh = Vt + ((size_t)(bidx * NH + h) * HDIM + hd) * S_LEN;
            short4v o0, o1;
            #pragma unroll
            for (int r = 0; r < 4; ++r) { o0[r] = f2bf(acc0[r] + bval); o1[r] = f2bf(acc1[r] + bval); }
            size_t s = s_base + 4 * g;
            *(short4v*)&Vh[s]      = o0;
            *(short4v*)&Vh[s + 16] = o1;
        }
    }
}

// ---------------------------------------------------------------------------
// K2: causal attention, block-level key-split, XCD-locality swizzle,
// HEAVY-FIRST dispatch (jq inverted), K-fragment software pipeline.
// Block = 4 waves on SAME (bh, 32 q-rows); wave w does k-tiles w, w+4, ...
// grid 2048.
// ---------------------------------------------------------------------------
__global__ __launch_bounds__(256) void attn_kernel(
    const short* __restrict__ Qp, const short* __restrict__ Kp,
    const short* __restrict__ Vt, short* __restrict__ Ab)
{
    __shared__ char smem[18432];               // pl / comb union
    __shared__ float psl[4][2][16];
    short (*pl)[32][72] = (short(*)[32][72])smem;
    float (*comb)[32][33] = (float(*)[32][33])smem;

    const int idx = blockIdx.x;
    const int bh = 4 * (idx & 7) + ((idx >> 3) & 3);
    const int jq = 63 - (idx >> 5);            // HEAVY FIRST
    const int b = bh >> 3, h = bh & 7;
    const int tid = threadIdx.x;
    const int w = tid >> 6, l = tid & 63, g = l >> 4, r15 = l & 15;
    const int q0 = jq * 32;

    const short* Qph = Qp + (size_t)bh * S_LEN * HDIM;
    const short* Kph = Kp + (size_t)bh * S_LEN * HDIM;
    const short* Vtp = Vt + (size_t)bh * HDIM * S_LEN;

    bf16x8 aq0 = *(const bf16x8*)&Qph[(size_t)(q0 + r15) * HDIM + 8 * g];
    bf16x8 aq1 = *(const bf16x8*)&Qph[(size_t)(q0 + 16 + r15) * HDIM + 8 * g];

    f32x4 oacc[2][2] = {};
    float ps0[4] = {}, ps1[4] = {};
    const f32x4 zero = {};
    const int ntiles = (q0 + 95) >> 6;

    // K software pipeline: prefetch tile kt's fragments one iteration ahead
    bf16x8 bkb[4];
    {
        const int k0 = w * 64;
        if (w < ntiles) {
            #pragma unroll
            for (int n = 0; n < 4; ++n)
                bkb[n] = *(const bf16x8*)&Kph[(size_t)(k0 + n * 16 + r15) * HDIM + 8 * g];
        }
    }

    for (int kt = w; kt < ntiles; kt += 4) {
        const int k0 = kt * 64;
        const bool full = (k0 + 63) <= q0;     // wave-uniform
        // prefetch next tile
        bf16x8 bkn[4];
        const int ktn = kt + 4;
        if (ktn < ntiles) {
            const int k0n = ktn * 64;
            #pragma unroll
            for (int n = 0; n < 4; ++n)
                bkn[n] = *(const bf16x8*)&Kph[(size_t)(k0n + n * 16 + r15) * HDIM + 8 * g];
        }

        __builtin_amdgcn_s_setprio(1);
        f32x4 s0v[4], s1v[4];
        #pragma unroll
        for (int n = 0; n < 4; ++n) {
            s0v[n] = __builtin_amdgcn_mfma_f32_16x16x32_bf16(aq0, bkb[n], zero, 0, 0, 0);
            s1v[n] = __builtin_amdgcn_mfma_f32_16x16x32_bf16(aq1, bkb[n], zero, 0, 0, 0);
        }
        __builtin_amdgcn_s_setprio(0);

        #pragma unroll
        for (int n = 0; n < 4; ++n) {
            int key = k0 + n * 16 + r15;
            if (full) {
                #pragma unroll
                for (int r = 0; r < 4; ++r) {
                    float e0 = __expf(s0v[n][r] * SCALE_);
                    float e1 = __expf(s1v[n][r] * SCALE_);
                    ps0[r] += e0; ps1[r] += e1;
                    pl[w][4 * g + r][n * 16 + r15]      = f2bf(e0);
                    pl[w][16 + 4 * g + r][n * 16 + r15] = f2bf(e1);
                }
            } else {
                #pragma unroll
                for (int r = 0; r < 4; ++r) {
                    int qr = q0 + 4 * g + r;
                    float e0 = (key <= qr)      ? __expf(s0v[n][r] * SCALE_) : 0.0f;
                    float e1 = (key <= qr + 16) ? __expf(s1v[n][r] * SCALE_) : 0.0f;
                    ps0[r] += e0; ps1[r] += e1;
                    pl[w][4 * g + r][n * 16 + r15]      = f2bf(e0);
                    pl[w][16 + 4 * g + r][n * 16 + r15] = f2bf(e1);
                }
            }
        }

        __builtin_amdgcn_s_setprio(1);
        #pragma unroll
        for (int ks = 0; ks < 2; ++ks) {
            bf16x8 pa0 = *(const bf16x8*)&pl[w][r15][ks * 32 + 8 * g];
            bf16x8 pa1 = *(const bf16x8*)&pl[w][16 + r15][ks * 32 + 8 * g];
            #pragma unroll
            for (int n2 = 0; n2 < 2; ++n2) {
                bf16x8 bv = *(const bf16x8*)&Vtp[(size_t)(n2 * 16 + r15) * S_LEN + k0 + ks * 32 + 8 * g];
                oacc[0][n2] = __builtin_amdgcn_mfma_f32_16x16x32_bf16(pa0, bv, oacc[0][n2], 0, 0, 0);
                oacc[1][n2] = __builtin_amdgcn_mfma_f32_16x16x32_bf16(pa1, bv, oacc[1][n2], 0, 0, 0);
            }
        }
        __builtin_amdgcn_s_setprio(0);

        if (ktn < ntiles) {
            #pragma unroll
            for (int n = 0; n < 4; ++n) bkb[n] = bkn[n];
        }
    }

    #pragma unroll
    for (int r = 0; r < 4; ++r) {
        float v0 = ps0[r], v1 = ps1[r];
        v0 += __shfl_xor(v0, 1); v1 += __shfl_xor(v1, 1);
        v0 += __shfl_xor(v0, 2); v1 += __shfl_xor(v1, 2);
        v0 += __shfl_xor(v0, 4); v1 += __shfl_xor(v1, 4);
        v0 += __shfl_xor(v0, 8); v1 += __shfl_xor(v1, 8);
        ps0[r] = v0; ps1[r] = v1;
    }

    __syncthreads();   // all waves done with pl -> reuse as comb
    #pragma unroll
    for (int n2 = 0; n2 < 2; ++n2) {
        #pragma unroll
        for (int r = 0; r < 4; ++r) {
            comb[w][4 * g + r][n2 * 16 + r15]      = oacc[0][n2][r];
            comb[w][16 + 4 * g + r][n2 * 16 + r15] = oacc[1][n2][r];
        }
    }
    if (r15 == 0) {
        #pragma unroll
        for (int r = 0; r < 4; ++r) {
            psl[w][0][4 * g + r] = ps0[r];
            psl[w][1][4 * g + r] = ps1[r];
        }
    }
    __syncthreads();

    {
        int q = tid >> 3, hd0 = (tid & 7) * 4;
        int qf = q >> 4, q15 = q & 15;
        float ps = psl[0][qf][q15] + psl[1][qf][q15] + psl[2][qf][q15] + psl[3][qf][q15];
        float inv = __fdividef(1.0f, ps);
        short4v o;
        #pragma unroll
        for (int j = 0; j < 4; ++j) {
            float v = comb[0][q][hd0 + j] + comb[1][q][hd0 + j]
                    + comb[2][q][hd0 + j] + comb[3][q][hd0 + j];
            o[j] = f2bf(v * inv);
        }
        *(short4v*)&Ab[((size_t)b * S_LEN + q0 + q) * D_MOD + h * HDIM + hd0] = o;
    }
}

// ---------------------------------------------------------------------------
// K3: output projection, streaming (no LDS).  Block = 4 waves over 32 rows;
// wave w = col-quarter, both row fragments.  grid 256.
// ---------------------------------------------------------------------------
__global__ __launch_bounds__(256) void out_proj_kernel(
    const short* __restrict__ Ab, const short* __restrict__ WTo,
    const float* __restrict__ bo, float* __restrict__ out)
{
    const int m0 = blockIdx.x * 32;
    const int tid = threadIdx.x;
    const int w = tid >> 6, l = tid & 63, g = l >> 4, r15 = l & 15;

    bf16x8 af[2][8];
    #pragma unroll
    for (int f = 0; f < 2; ++f)
        #pragma unroll
        for (int kk = 0; kk < 8; ++kk)
            af[f][kk] = *(const bf16x8*)&Ab[(size_t)(m0 + f * 16 + r15) * D_MOD + kk * 32 + 8 * g];

    #pragma unroll
    for (int ntl = 0; ntl < 4; ++ntl) {
        int col = w * 64 + ntl * 16 + r15;
        f32x4 acc0 = {}, acc1 = {};
        #pragma unroll
        for (int kk = 0; kk < 8; ++kk) {
            bf16x8 bfr = *(const bf16x8*)&WTo[(size_t)col * 256 + kk * 32 + 8 * g];
            acc0 = __builtin_amdgcn_mfma_f32_16x16x32_bf16(af[0][kk], bfr, acc0, 0, 0, 0);
            acc1 = __builtin_amdgcn_mfma_f32_16x16x32_bf16(af[1][kk], bfr, acc1, 0, 0, 0);
        }
        float bval = bo[col];
        #pragma unroll
        for (int r = 0; r < 4; ++r) {
            out[(size_t)(m0 + 4 * g + r) * D_MOD + col]      = acc0[r] + bval;
            out[(size_t)(m0 + 16 + 4 * g + r) * D_MOD + col] = acc1[r] + bval;
        }
    }
}

extern "C" void kernel_launch(void* const* d_in, const int* in_sizes, int n_in,
                              void* d_out, int out_size, void* d_ws, size_t ws_size,
                              hipStream_t stream) {
    const float* q_in = (const float*)d_in[0];
    const float* k_in = (const float*)d_in[1];
    const float* v_in = (const float*)d_in[2];
    // d_in[3] = mask: causal tril, applied analytically.
    const float* Wq = (const float*)d_in[4];
    const float* bq = (const float*)d_in[5];
    const float* Wk = (const float*)d_in[6];
    const float* bk = (const float*)d_in[7];
    const float* Wv = (const float*)d_in[8];
    const float* bv = (const float*)d_in[9];
    const float* Wo = (const float*)d_in[10];
    const float* bo = (const float*)d_in[11];
    float* out = (float*)d_out;

    const size_t NTOK = (size_t)BATCH * S_LEN * D_MOD;  // 2M elements
    short* WT = (short*)d_ws;           // 4 x 256 x 256 bf16 = 512 KB
    short* Qp = WT + 4 * 65536;         // packed [bh][s][32]
    short* Kp = Qp + NTOK;              // packed [bh][s][32]
    short* Vt = Kp + NTOK;              // transposed [bh][hd][s]
    short* Ab = Vt + NTOK;              // [b][s][256]

    wtrans_kernel<<<dim3(4, 32), 256, 0, stream>>>(Wq, Wk, Wv, Wo, WT);
    qkv_proj_kernel<<<dim3(256, 3), 256, 0, stream>>>(
        q_in, k_in, v_in, WT, bq, bk, bv, Qp, Kp, Vt);
    attn_kernel<<<2048, 256, 0, stream>>>(Qp, Kp, Vt, Ab);
    out_proj_kernel<<<256, 256, 0, stream>>>(Ab, WT + 3 * 65536, bo, out);
}